// Round 1
// baseline (106.275 us; speedup 1.0000x reference)
//
#include <hip/hip_runtime.h>
#include <hip/hip_bf16.h>

// GATConv reduces algebraically to a permuted-column GEMM:
//   out[n, c] = sum_k x[n,k] * W[(c%8)*64 + c/8, k] + bias[c]
// (the reference einsum contracts alpha over its softmax axis -> sum == 1).
// N=4096, K=256, M=512. bf16 MFMA version.
//
// R1 change vs previous: A tile has NO cross-wave reuse (each wave owns its
// 16 rows, and each afrag is register-reused 4x), so staging A through LDS
// was pure overhead: 16 short4 LDS writes/thread + 8 ds_read_b128/lane +
// double LDS footprint + A on the barrier critical path. A now goes
// global -> VGPR -> bf16 directly; only B (4-wave reuse) stays in LDS.

typedef __attribute__((ext_vector_type(8))) short bf16x8;   // 8 bf16 (4 VGPRs)
typedef __attribute__((ext_vector_type(4))) float floatx4;  // MFMA accumulator

#define BM 64
#define BN 64
#define LDK 264   // row stride in bf16 elems: 264*2B = 528B = 132 dwords -> 4-bank/row advance, 16B-aligned rows

__device__ __forceinline__ short f2bf(float f) {
    union { __hip_bfloat16 h; short s; } u;
    u.h = __float2bfloat16(f);   // RNE
    return u.s;
}

__global__ __launch_bounds__(256) void gat_gemm(
    const float* __restrict__ x,    // [4096, 256]
    const float* __restrict__ W,    // [512, 256]
    const float* __restrict__ bias, // [512]
    float* __restrict__ out)        // [4096, 512]
{
    __shared__ short Bs[BN][LDK];   // permuted-W tile, bf16 (B^T row-major)

    const int tid = threadIdx.x;       // 0..255
    const int rowBase = blockIdx.y * BM;
    const int colBase = blockIdx.x * BN;

    const int wave = tid >> 6;         // 0..3
    const int lane = tid & 63;
    const int mrow = lane & 15;        // row within A tile / col within B tile
    const int quad = lane >> 4;        // 0..3 -> k-subblock (input), row-subblock (output)
    const int arow = wave * 16 + mrow;

    // ---- A: global -> registers, no LDS round trip ----
    // lane's afrag for k-block kb lives at x[(rowBase+arow)*256 + kb*32 + quad*8]
    // (identical values/layout to the old As[arow][kb*32+quad*8] read).
    const float* xrow = &x[(rowBase + arow) * 256 + quad * 8];
    float4 a[16];
    #pragma unroll
    for (int kb = 0; kb < 8; ++kb) {
        a[2 * kb]     = *(const float4*)(xrow + kb * 32);
        a[2 * kb + 1] = *(const float4*)(xrow + kb * 32 + 4);
    }

    // hoist bias (latency hidden under the stage phase)
    float bv0 = bias[colBase + 0 * 16 + mrow];
    float bv1 = bias[colBase + 1 * 16 + mrow];
    float bv2 = bias[colBase + 2 * 16 + mrow];
    float bv3 = bias[colBase + 3 * 16 + mrow];

    // ---- B stage: 64x256 fp32 -> bf16 into LDS ----
    // 64*256/4 = 4096 float4 per tile; 16 float4/thread.
    #pragma unroll
    for (int l = 0; l < 16; ++l) {
        int f  = tid + l * 256;    // float4 index 0..4095
        int r  = f >> 6;           // tile row 0..63
        int c4 = f & 63;           // float4 within row (k/4)
        int col  = colBase + r;
        int wrow = ((col & 7) << 6) + (col >> 3);    // perm(c)
        float4 bv = *(const float4*)&W[wrow * 256 + c4 * 4];
        short4 b; b.x = f2bf(bv.x); b.y = f2bf(bv.y); b.z = f2bf(bv.z); b.w = f2bf(bv.w);
        *(short4*)&Bs[r][c4 * 4] = b;
    }

    // ---- convert A in-register (A loads landed under the B stage) ----
    bf16x8 afrag[8];
    #pragma unroll
    for (int kb = 0; kb < 8; ++kb) {
        bf16x8 t;
        t[0] = f2bf(a[2 * kb].x);     t[1] = f2bf(a[2 * kb].y);
        t[2] = f2bf(a[2 * kb].z);     t[3] = f2bf(a[2 * kb].w);
        t[4] = f2bf(a[2 * kb + 1].x); t[5] = f2bf(a[2 * kb + 1].y);
        t[6] = f2bf(a[2 * kb + 1].z); t[7] = f2bf(a[2 * kb + 1].w);
        afrag[kb] = t;
    }

    __syncthreads();

    // ---- compute: each wave owns a 16-row slab, 4 col tiles of 16 ----
    floatx4 acc[4] = {floatx4{0,0,0,0}, floatx4{0,0,0,0},
                      floatx4{0,0,0,0}, floatx4{0,0,0,0}};

    #pragma unroll
    for (int kb = 0; kb < 8; ++kb) {
        int koff = kb * 32 + quad * 8;                 // bf16 elem offset, 16B-aligned
        #pragma unroll
        for (int t = 0; t < 4; ++t) {
            bf16x8 bfrag = *(const bf16x8*)&Bs[t * 16 + mrow][koff];
            acc[t] = __builtin_amdgcn_mfma_f32_16x16x32_bf16(afrag[kb], bfrag, acc[t], 0, 0, 0);
        }
    }

    // ---- epilogue: C/D layout col=lane&15, row=quad*4+reg ----
    float bvs[4] = {bv0, bv1, bv2, bv3};
    #pragma unroll
    for (int t = 0; t < 4; ++t) {
        int col = colBase + t * 16 + mrow;
        #pragma unroll
        for (int r = 0; r < 4; ++r) {
            int row = rowBase + wave * 16 + quad * 4 + r;
            out[row * 512 + col] = acc[t][r] + bvs[t];
        }
    }
}

extern "C" void kernel_launch(void* const* d_in, const int* in_sizes, int n_in,
                              void* d_out, int out_size, void* d_ws, size_t ws_size,
                              hipStream_t stream) {
    // setup_inputs order: 0=adj (unused), 1=x, 2=W, 3=att_src (unused),
    //                     4=att_dst (unused), 5=bias
    const float* x    = (const float*)d_in[1];
    const float* W    = (const float*)d_in[2];
    const float* bias = (const float*)d_in[5];
    float* out        = (float*)d_out;

    dim3 grid(512 / BN, 4096 / BM);  // 8 x 64 = 512 blocks
    dim3 block(256);
    hipLaunchKernelGGL(gat_gemm, grid, block, 0, stream, x, W, bias, out);
}